// Round 2
// baseline (324.173 us; speedup 1.0000x reference)
//
#include <hip/hip_runtime.h>

#define B_TOTAL 32768
#define NATOM   512
#define MDIM    64
#define KS      5

// ---------------------------------------------------------------------------
// K0: materialize data^T: dataT[m][b] = z_perm_flat[m*32768+b]
// where z_perm = transpose(z_e,(0,2,3,1)), reshaped row-major to (64, 32768).
// Mapping: for z_e[n,c,h,w]:  m = 2n + (h>>4),  b = ((h&15)<<11)|(w<<6)|c.
// LDS tile transpose; reads and writes both 256B-coalesced.
// ---------------------------------------------------------------------------
__global__ void k_perm(const float* __restrict__ ze, float* __restrict__ dT) {
    const int n   = blockIdx.x >> 4;          // 32 n
    const int hw0 = (blockIdx.x & 15) * 64;   // 16 hw-tiles of 64
    const int t   = threadIdx.x;
    __shared__ float lds[64][65];
#pragma unroll
    for (int r = 0; r < 16; ++r) {
        int id = r * 256 + t;
        int c = id >> 6, i = id & 63;         // consecutive t -> consecutive i
        lds[c][i] = ze[n * 65536 + c * 1024 + hw0 + i];
    }
    __syncthreads();
#pragma unroll
    for (int r = 0; r < 16; ++r) {
        int id = r * 256 + t;
        int c = id & 63, j = id >> 6;         // consecutive t -> consecutive c
        int hw = hw0 + j;
        int h = hw >> 5, w = hw & 31;
        int m = (n << 1) | (h >> 4);
        int b = ((h & 15) << 11) | (w << 6) | c;
        dT[m * 32768 + b] = lds[c][j];
    }
}

// ---------------------------------------------------------------------------
// K1: G = D^T D  (512x512), also zero the loss accumulator.
// ---------------------------------------------------------------------------
__global__ void k_gram(const float* __restrict__ D, float* __restrict__ G,
                       float* __restrict__ acc) {
    const int i = blockIdx.x;          // 512 blocks, one G row each
    const int t = threadIdx.x;         // 256 threads
    __shared__ float col[MDIM];
    if (t < MDIM) col[t] = D[t * NATOM + i];
    __syncthreads();
    for (int j = t; j < NATOM; j += 256) {
        float s = 0.f;
#pragma unroll
        for (int m = 0; m < MDIM; ++m) s = fmaf(col[m], D[m * NATOM + j], s);
        G[i * NATOM + j] = s;
    }
    if (i == 0 && t == 0) *acc = 0.f;
}

// ---------------------------------------------------------------------------
// K2: fused h_bar GEMM + per-column OMP.
// Block = 256 threads = 4 waves; block covers 32 consecutive b; wave handles 8 b.
// Lane l owns atoms n = 256*j + 4*l + s  (j in {0,1}, s in {0..3}) -> 8 per lane.
// ---------------------------------------------------------------------------
__launch_bounds__(256)
__global__ void k_omp(const float* __restrict__ data, const float* __restrict__ D,
                      const float* __restrict__ G, int* __restrict__ idx_out,
                      float* __restrict__ val_out) {
    const int t    = threadIdx.x;
    const int lane = t & 63;
    const int wv   = t >> 6;              // 0..3
    const int b0   = blockIdx.x * 32;

    __shared__ __align__(16) float data_s[32][68];   // [bb][m], padded
    __shared__ int   idx_s[KS][32];
    __shared__ float val_s[KS][32];

    // stage data tile (64 m x 32 b), coalesced on b
#pragma unroll
    for (int r = 0; r < 8; ++r) {
        int id = r * 256 + t;
        int m = id >> 5, bb = id & 31;
        data_s[bb][m] = data[m * B_TOTAL + b0 + bb];
    }
    __syncthreads();

    const float4* __restrict__ D4 = (const float4*)D;   // D[m][n], n4 = n/4
    const float4* __restrict__ G4 = (const float4*)G;

    // ---- phase 1: h_bar accumulators, 8 b x (2 j x 4 s) per lane ----
    float4 acc[8][2];
#pragma unroll
    for (int bb = 0; bb < 8; ++bb) {
        acc[bb][0] = make_float4(0.f, 0.f, 0.f, 0.f);
        acc[bb][1] = make_float4(0.f, 0.f, 0.f, 0.f);
    }
    const int bwbase = wv * 8;

#pragma unroll 4
    for (int c = 0; c < 16; ++c) {        // 4 m per chunk, ascending m order
        float4 df[4][2];
#pragma unroll
        for (int mm = 0; mm < 4; ++mm) {
            df[mm][0] = D4[(c * 4 + mm) * 128 + lane];
            df[mm][1] = D4[(c * 4 + mm) * 128 + 64 + lane];
        }
#pragma unroll
        for (int bb = 0; bb < 8; ++bb) {
            const float4 dv = *(const float4*)&data_s[bwbase + bb][c * 4];
            const float dm[4] = {dv.x, dv.y, dv.z, dv.w};
#pragma unroll
            for (int mm = 0; mm < 4; ++mm) {
                acc[bb][0].x = fmaf(df[mm][0].x, dm[mm], acc[bb][0].x);
                acc[bb][0].y = fmaf(df[mm][0].y, dm[mm], acc[bb][0].y);
                acc[bb][0].z = fmaf(df[mm][0].z, dm[mm], acc[bb][0].z);
                acc[bb][0].w = fmaf(df[mm][0].w, dm[mm], acc[bb][0].w);
                acc[bb][1].x = fmaf(df[mm][1].x, dm[mm], acc[bb][1].x);
                acc[bb][1].y = fmaf(df[mm][1].y, dm[mm], acc[bb][1].y);
                acc[bb][1].z = fmaf(df[mm][1].z, dm[mm], acc[bb][1].z);
                acc[bb][1].w = fmaf(df[mm][1].w, dm[mm], acc[bb][1].w);
            }
        }
    }

    // ---- phase 2: OMP per b (wave-sequential over its 8 b's) ----
#pragma unroll 1
    for (int bb = 0; bb < 8; ++bb) {
        const float4 hq0 = acc[0][0], hq1 = acc[0][1];
#pragma unroll
        for (int i = 0; i < 7; ++i) { acc[i][0] = acc[i + 1][0]; acc[i][1] = acc[i + 1][1]; }

        float hb[8] = {hq0.x, hq0.y, hq0.z, hq0.w, hq1.x, hq1.y, hq1.z, hq1.w};
        float h[8];
#pragma unroll
        for (int e = 0; e < 8; ++e) h[e] = hb[e];

        unsigned maskbits = 0;
        int   I[KS];
        float gsel[KS];
        float xs[KS];
        float Lm[15];                 // packed lower-tri, row-major
        float Grow[KS][8];            // cached G rows of selected atoms

#pragma unroll
        for (int k = 0; k < KS; ++k) {
            // --- argmax |h|*~mask, lowest index on ties (matches jnp.argmax) ---
            float bv = -1.f; int bn = 0x7fffffff;
#pragma unroll
            for (int e = 0; e < 8; ++e) {
                float v = ((maskbits >> e) & 1u) ? -1.f : fabsf(h[e]);
                int n = ((e >> 2) << 8) + (lane << 2) + (e & 3);
                if (v > bv) { bv = v; bn = n; }     // ascending n within lane
            }
#pragma unroll
            for (int off = 32; off > 0; off >>= 1) {
                float ov = __shfl_xor(bv, off);
                int   on = __shfl_xor(bn, off);
                if (ov > bv || (ov == bv && on < bn)) { bv = ov; bn = on; }
            }
            const int nsel = bn;      // wave-uniform

            // mask the selected atom
            if (((nsel & 255) >> 2) == lane)
                maskbits |= 1u << ((((unsigned)nsel >> 8) << 2) | (nsel & 3));

            // --- Cholesky update of L ---
            if (k > 0) {
                float g[4], w[4];
#pragma unroll
                for (int ti = 0; ti < k; ++ti) g[ti] = G[I[ti] * NATOM + nsel];
#pragma unroll
                for (int r = 0; r < k; ++r) {
                    float s = g[r];
#pragma unroll
                    for (int cc = 0; cc < r; ++cc) s -= Lm[r * (r + 1) / 2 + cc] * w[cc];
                    w[r] = s / Lm[r * (r + 1) / 2 + r];
                }
                float s2 = 0.f;
#pragma unroll
                for (int r = 0; r < k; ++r) s2 += w[r] * w[r];
                float wc = sqrtf(fmaxf(0.f, 1.f - s2));
#pragma unroll
                for (int cc = 0; cc < k; ++cc) Lm[k * (k + 1) / 2 + cc] = w[cc];
                Lm[k * (k + 1) / 2 + k] = wc;
            } else {
                Lm[0] = 1.f;
            }
            I[k] = nsel;

            // --- extract h_bar[nsel] (static-index select + shfl) ---
            {
                const int sl = (nsel & 255) >> 2;
                const int ss = nsel & 3;
                const int jj = nsel >> 8;
                float v0 = (ss == 0) ? hb[0] : (ss == 1) ? hb[1] : (ss == 2) ? hb[2] : hb[3];
                float v1 = (ss == 0) ? hb[4] : (ss == 1) ? hb[5] : (ss == 2) ? hb[6] : hb[7];
                float vv = jj ? v1 : v0;
                gsel[k] = __shfl(vv, sl);
            }

            // --- cache G row of the new atom (coalesced float4 loads) ---
            {
                float4 g0 = G4[nsel * 128 + lane];
                float4 g1 = G4[nsel * 128 + 64 + lane];
                Grow[k][0] = g0.x; Grow[k][1] = g0.y; Grow[k][2] = g0.z; Grow[k][3] = g0.w;
                Grow[k][4] = g1.x; Grow[k][5] = g1.y; Grow[k][6] = g1.z; Grow[k][7] = g1.w;
            }

            // --- solve L y = h_bar[I]; L^T x = y (replicated per lane) ---
            float y[KS];
#pragma unroll
            for (int r = 0; r <= k; ++r) {
                float s = gsel[r];
#pragma unroll
                for (int cc = 0; cc < r; ++cc) s -= Lm[r * (r + 1) / 2 + cc] * y[cc];
                y[r] = s / Lm[r * (r + 1) / 2 + r];
            }
#pragma unroll
            for (int r = k; r >= 0; --r) {
                float s = y[r];
#pragma unroll
                for (int cc = r + 1; cc <= k; ++cc) s -= Lm[cc * (cc + 1) / 2 + r] * xs[cc];
                xs[r] = s / Lm[r * (r + 1) / 2 + r];
            }

            // --- h = h_bar - G[:,I] x (beta recomputed like the reference) ---
            if (k < KS - 1) {
#pragma unroll
                for (int e = 0; e < 8; ++e) {
                    float beta = 0.f;
#pragma unroll
                    for (int ti = 0; ti <= k; ++ti) beta = fmaf(xs[ti], Grow[ti][e], beta);
                    h[e] = hb[e] - beta;
                }
            }
        }

        if (lane == 0) {
#pragma unroll
            for (int k = 0; k < KS; ++k) {
                idx_s[k][bwbase + bb] = I[k];
                val_s[k][bwbase + bb] = xs[k];
            }
        }
    }

    __syncthreads();
    if (t < KS * 32) {
        int k = t >> 5, bb = t & 31;
        idx_out[k * B_TOTAL + b0 + bb] = idx_s[k][bb];
        val_out[k * B_TOTAL + b0 + bb] = val_s[k][bb];
    }
}

// ---------------------------------------------------------------------------
// K3a: expand sparse (idx,val) into the dense 512 x 32768 coefficient output.
// Fully coalesced dword stores.
// ---------------------------------------------------------------------------
__global__ void k_coeff(const int* __restrict__ idx, const float* __restrict__ val,
                        float* __restrict__ coeff) {
    const int bblk = blockIdx.x >> 3;
    const int jc   = blockIdx.x & 7;
    const int b    = bblk * 256 + threadIdx.x;
    int   I[KS]; float V[KS];
#pragma unroll
    for (int k = 0; k < KS; ++k) {
        I[k] = idx[k * B_TOTAL + b];
        V[k] = val[k * B_TOTAL + b];
    }
    const int j0 = jc * 64;
#pragma unroll 4
    for (int j = j0; j < j0 + 64; ++j) {
        float w = 0.f;
#pragma unroll
        for (int k = 0; k < KS; ++k) w = (I[k] == j) ? V[k] : w;
        coeff[j * B_TOTAL + b] = w;
    }
}

// ---------------------------------------------------------------------------
// K3b: z_out (in z_e layout, coalesced) + loss partial sums.
// g = n*65536 + c*1024 + hw ;  f = n*65536 + hw*64 + c ; m = f>>15, b = f&32767.
// ---------------------------------------------------------------------------
__global__ void k_recon(const float* __restrict__ ze, const float* __restrict__ D,
                        const int* __restrict__ idx, const float* __restrict__ val,
                        float* __restrict__ zout, float* __restrict__ acc) {
    const int g  = blockIdx.x * 256 + threadIdx.x;
    const int n  = g >> 16;
    const int c  = (g >> 10) & 63;
    const int hw = g & 1023;
    const int f  = (n << 16) + (hw << 6) + c;
    const int b  = f & 32767;
    const int m  = f >> 15;

    float zdl = 0.f;
#pragma unroll
    for (int k = 0; k < KS; ++k) {
        int   a = idx[k * B_TOTAL + b];
        float v = val[k * B_TOTAL + b];
        zdl = fmaf(v, D[m * NATOM + a], zdl);
    }
    const float zp   = ze[g];
    const float diff = zdl - zp;
    zout[g] = zp + diff;            // z_perm + (z_dl - z_perm), same fp order as ref

    float sq = diff * diff;
#pragma unroll
    for (int off = 32; off > 0; off >>= 1) sq += __shfl_xor(sq, off);
    __shared__ float red[4];
    if ((threadIdx.x & 63) == 0) red[threadIdx.x >> 6] = sq;
    __syncthreads();
    if (threadIdx.x == 0) atomicAdd(acc, red[0] + red[1] + red[2] + red[3]);
}

// ---------------------------------------------------------------------------
// K4: finalize loss = 1.25 * mean(diff^2)
// ---------------------------------------------------------------------------
__global__ void k_loss(const float* __restrict__ acc, float* __restrict__ out_loss) {
    if (threadIdx.x == 0 && blockIdx.x == 0)
        *out_loss = 1.25f * (*acc / 2097152.f);
}

// ---------------------------------------------------------------------------
extern "C" void kernel_launch(void* const* d_in, const int* in_sizes, int n_in,
                              void* d_out, int out_size, void* d_ws, size_t ws_size,
                              hipStream_t stream) {
    const float* ze = (const float*)d_in[0];   // (32,64,32,32) fp32 = 2097152
    const float* D  = (const float*)d_in[1];   // (64,512) fp32

    // ws layout (floats): G [0,262144) | idx | val | acc | dataT (2097152)
    float* G     = (float*)d_ws;
    int*   idxp  = (int*)  ((char*)d_ws + (size_t)262144 * 4);
    float* valp  = (float*)((char*)d_ws + (size_t)(262144 + 163840) * 4);
    float* accp  = (float*)((char*)d_ws + (size_t)(262144 + 2 * 163840) * 4);
    float* dataT = (float*)((char*)d_ws + (size_t)(262144 + 2 * 163840 + 64) * 4);

    float* zout  = (float*)d_out;              // 2097152
    float* lossp = zout + 2097152;             // 1
    float* coeff = zout + 2097153;             // 512*32768

    k_perm <<<512, 256, 0, stream>>>(ze, dataT);
    k_gram <<<512, 256, 0, stream>>>(D, G, accp);
    k_omp  <<<1024, 256, 0, stream>>>(dataT, D, G, idxp, valp);
    k_coeff<<<1024, 256, 0, stream>>>(idxp, valp, coeff);
    k_recon<<<8192, 256, 0, stream>>>(ze, D, idxp, valp, zout, accp);
    k_loss <<<1, 64, 0, stream>>>(accp, lossp);
}

// Round 3
// 295.275 us; speedup vs baseline: 1.0979x; 1.0979x over previous
//
#include <hip/hip_runtime.h>

#define B_TOTAL 32768
#define NATOM   512
#define MDIM    64
#define KS      5

// ---------------------------------------------------------------------------
// K0: materialize data^T: dataT[m][b] = z_perm_flat[m*32768+b]
// z_perm = transpose(z_e,(0,2,3,1)) reshaped row-major to (64, 32768).
// For z_e[n,c,h,w]:  m = 2n + (h>>4),  b = ((h&15)<<11)|(w<<6)|c.
// ---------------------------------------------------------------------------
__global__ void k_perm(const float* __restrict__ ze, float* __restrict__ dT) {
    const int n   = blockIdx.x >> 4;
    const int hw0 = (blockIdx.x & 15) * 64;
    const int t   = threadIdx.x;
    __shared__ float lds[64][65];
#pragma unroll
    for (int r = 0; r < 16; ++r) {
        int id = r * 256 + t;
        int c = id >> 6, i = id & 63;
        lds[c][i] = ze[n * 65536 + c * 1024 + hw0 + i];
    }
    __syncthreads();
#pragma unroll
    for (int r = 0; r < 16; ++r) {
        int id = r * 256 + t;
        int c = id & 63, j = id >> 6;
        int hw = hw0 + j;
        int h = hw >> 5, w = hw & 31;
        int m = (n << 1) | (h >> 4);
        int b = ((h & 15) << 11) | (w << 6) | c;
        dT[m * 32768 + b] = lds[c][j];
    }
}

// ---------------------------------------------------------------------------
// K1: G = D^T D, zero loss accumulator.
// ---------------------------------------------------------------------------
__global__ void k_gram(const float* __restrict__ D, float* __restrict__ G,
                       float* __restrict__ acc) {
    const int i = blockIdx.x;
    const int t = threadIdx.x;
    __shared__ float col[MDIM];
    if (t < MDIM) col[t] = D[t * NATOM + i];
    __syncthreads();
    for (int j = t; j < NATOM; j += 256) {
        float s = 0.f;
#pragma unroll
        for (int m = 0; m < MDIM; ++m) s = fmaf(col[m], D[m * NATOM + j], s);
        G[i * NATOM + j] = s;
    }
    if (i == 0 && t == 0) *acc = 0.f;
}

// ---------------------------------------------------------------------------
// K2: fused h_bar GEMM + per-column OMP.
// Phase 1: block = 4 waves, 32 b; wave computes h_bar for its 8 b
//   (lane l holds atoms n = 256j+4l+s, 8 per lane).
// Re-stage via wave-private LDS so each 8-lane group owns ONE b with
//   64 atoms/lane (lane p holds atoms n = 32q+4p+s, q=0..15).
// Phase 2: all 8 b of a wave run CONCURRENTLY (one per group).
// ---------------------------------------------------------------------------
__launch_bounds__(256, 3)
__global__ void k_omp(const float* __restrict__ data, const float* __restrict__ D,
                      const float* __restrict__ G, int* __restrict__ idx_out,
                      float* __restrict__ val_out) {
    const int t    = threadIdx.x;
    const int lane = t & 63;
    const int wv   = t >> 6;
    const int b0   = blockIdx.x * 32;

    __shared__ __align__(16) float data_s[32][68];
    __shared__ __align__(16) float stage[4][2048];   // 8KB per wave
    __shared__ int   idx_s[KS][32];
    __shared__ float val_s[KS][32];

    // stage data tile (64 m x 32 b), coalesced on b
#pragma unroll
    for (int r = 0; r < 8; ++r) {
        int id = r * 256 + t;
        int m = id >> 5, bb = id & 31;
        data_s[bb][m] = data[m * B_TOTAL + b0 + bb];
    }
    __syncthreads();

    const float4* __restrict__ D4 = (const float4*)D;
    const float4* __restrict__ G4 = (const float4*)G;

    // ---- phase 1: h_bar accumulators, 8 b x 8 atoms per lane ----
    float4 acc[8][2];
#pragma unroll
    for (int bb = 0; bb < 8; ++bb) {
        acc[bb][0] = make_float4(0.f, 0.f, 0.f, 0.f);
        acc[bb][1] = make_float4(0.f, 0.f, 0.f, 0.f);
    }
    const int bwbase = wv * 8;

#pragma unroll 4
    for (int c = 0; c < 16; ++c) {
        float4 df[4][2];
#pragma unroll
        for (int mm = 0; mm < 4; ++mm) {
            df[mm][0] = D4[(c * 4 + mm) * 128 + lane];
            df[mm][1] = D4[(c * 4 + mm) * 128 + 64 + lane];
        }
#pragma unroll
        for (int bb = 0; bb < 8; ++bb) {
            const float4 dv = *(const float4*)&data_s[bwbase + bb][c * 4];
            const float dm[4] = {dv.x, dv.y, dv.z, dv.w};
#pragma unroll
            for (int mm = 0; mm < 4; ++mm) {
                acc[bb][0].x = fmaf(df[mm][0].x, dm[mm], acc[bb][0].x);
                acc[bb][0].y = fmaf(df[mm][0].y, dm[mm], acc[bb][0].y);
                acc[bb][0].z = fmaf(df[mm][0].z, dm[mm], acc[bb][0].z);
                acc[bb][0].w = fmaf(df[mm][0].w, dm[mm], acc[bb][0].w);
                acc[bb][1].x = fmaf(df[mm][1].x, dm[mm], acc[bb][1].x);
                acc[bb][1].y = fmaf(df[mm][1].y, dm[mm], acc[bb][1].y);
                acc[bb][1].z = fmaf(df[mm][1].z, dm[mm], acc[bb][1].z);
                acc[bb][1].w = fmaf(df[mm][1].w, dm[mm], acc[bb][1].w);
            }
        }
    }

    // ---- re-stage: acc(8b x 8 atoms) -> hb(64 atoms of group's b) ----
    // wave-private region; within-wave DS ordering makes this barrier-free.
    const int g = lane >> 3;       // group = b within wave's 8
    const int p = lane & 7;        // lane within group
    float hb[64];
#pragma unroll
    for (int r = 0; r < 2; ++r) {
#pragma unroll
        for (int q2 = 0; q2 < 4; ++q2) {
            int bb = r * 4 + q2;
            *(float4*)&stage[wv][q2 * 512 + 4 * lane]       = acc[bb][0];
            *(float4*)&stage[wv][q2 * 512 + 256 + 4 * lane] = acc[bb][1];
        }
        if ((g >> 2) == r) {
#pragma unroll
            for (int q = 0; q < 16; ++q)
                *(float4*)&hb[4 * q] =
                    *(const float4*)&stage[wv][(g & 3) * 512 + 32 * q + 4 * p];
        }
    }

    // ---- phase 2: OMP, 8 concurrent b (one per 8-lane group) ----
    float key[64];
#pragma unroll
    for (int e = 0; e < 64; ++e) key[e] = fabsf(hb[e]);

    unsigned msk0 = 0u, msk1 = 0u;
    int   I[KS];
    float xs[KS];
    float gsel[KS];
    float Lm[15];                   // packed lower-tri

#pragma unroll
    for (int k = 0; k < KS; ++k) {
        // --- local argmax over 64 register keys (mask pre-folded as -1) ---
        float bv = key[0]; int be = 0; float bhb = hb[0];
#pragma unroll
        for (int e = 1; e < 64; ++e) {
            bool gt = key[e] > bv;          // strict > keeps lowest e (n asc.)
            bv  = gt ? key[e] : bv;
            be  = gt ? e      : be;
            bhb = gt ? hb[e]  : bhb;
        }
        int bn = 32 * (be >> 2) + 4 * p + (be & 3);
        // --- 3-step reduce across the 8-lane group ---
#pragma unroll
        for (int off = 1; off < 8; off <<= 1) {
            float ov  = __shfl_xor(bv, off);
            int   on  = __shfl_xor(bn, off);
            float ohb = __shfl_xor(bhb, off);
            bool take = (ov > bv) || (ov == bv && on < bn);
            bv = take ? ov : bv; bn = take ? on : bn; bhb = take ? ohb : bhb;
        }
        const int nsel = bn;                // group-uniform
        I[k]    = nsel;
        gsel[k] = bhb;                      // = h_bar[nsel], exact

        // mask the selected atom for future scans
        {
            int own  = (nsel >> 2) & 7;
            int esel = ((nsel >> 5) << 2) | (nsel & 3);
            if (p == own) {
                if (esel < 32) msk0 |= 1u << esel;
                else           msk1 |= 1u << (esel - 32);
            }
        }

        // --- Cholesky update of L ---
        if (k > 0) {
            float gk[KS - 1], w[KS - 1];
#pragma unroll
            for (int ti = 0; ti < KS - 1; ++ti)
                if (ti < k) gk[ti] = G[I[ti] * NATOM + nsel];
#pragma unroll
            for (int r = 0; r < KS - 1; ++r) {
                if (r < k) {
                    float s = gk[r];
#pragma unroll
                    for (int cc = 0; cc < KS - 1; ++cc)
                        if (cc < r) s -= Lm[r * (r + 1) / 2 + cc] * w[cc];
                    w[r] = s / Lm[r * (r + 1) / 2 + r];
                }
            }
            float s2 = 0.f;
#pragma unroll
            for (int r = 0; r < KS - 1; ++r) if (r < k) s2 += w[r] * w[r];
            float wc = sqrtf(fmaxf(0.f, 1.f - s2));
#pragma unroll
            for (int cc = 0; cc < KS - 1; ++cc)
                if (cc < k) Lm[k * (k + 1) / 2 + cc] = w[cc];
            Lm[k * (k + 1) / 2 + k] = wc;
        } else {
            Lm[0] = 1.f;
        }

        // --- solve L y = gsel ; L^T x = y (replicated within group) ---
        float y[KS];
#pragma unroll
        for (int r = 0; r <= k; ++r) {
            float s = gsel[r];
#pragma unroll
            for (int cc = 0; cc < r; ++cc) s -= Lm[r * (r + 1) / 2 + cc] * y[cc];
            y[r] = s / Lm[r * (r + 1) / 2 + r];
        }
#pragma unroll
        for (int r = k; r >= 0; --r) {
            float s = y[r];
#pragma unroll
            for (int cc = r + 1; cc <= k; ++cc) s -= Lm[cc * (cc + 1) / 2 + r] * xs[cc];
            xs[r] = s / Lm[r * (r + 1) / 2 + r];
        }

        // --- beta recompute (stream G rows) + next argmax keys ---
        if (k < KS - 1) {
            float beta[64];
#pragma unroll
            for (int ti = 0; ti <= k; ++ti) {
                const float4* __restrict__ Gr = &G4[I[ti] * 128 + p];
#pragma unroll
                for (int q = 0; q < 16; ++q) {
                    float4 gc = Gr[8 * q];
                    if (ti == 0) {
                        beta[4 * q + 0] = xs[0] * gc.x;
                        beta[4 * q + 1] = xs[0] * gc.y;
                        beta[4 * q + 2] = xs[0] * gc.z;
                        beta[4 * q + 3] = xs[0] * gc.w;
                    } else {
                        beta[4 * q + 0] = fmaf(xs[ti], gc.x, beta[4 * q + 0]);
                        beta[4 * q + 1] = fmaf(xs[ti], gc.y, beta[4 * q + 1]);
                        beta[4 * q + 2] = fmaf(xs[ti], gc.z, beta[4 * q + 2]);
                        beta[4 * q + 3] = fmaf(xs[ti], gc.w, beta[4 * q + 3]);
                    }
                }
            }
#pragma unroll
            for (int e = 0; e < 64; ++e) {
                float d = hb[e] - beta[e];
                bool msk = (e < 32) ? ((msk0 >> e) & 1u) : ((msk1 >> (e - 32)) & 1u);
                key[e] = msk ? -1.f : fabsf(d);
            }
        }
    }

    if (p == 0) {
#pragma unroll
        for (int k = 0; k < KS; ++k) {
            idx_s[k][wv * 8 + g] = I[k];
            val_s[k][wv * 8 + g] = xs[k];
        }
    }
    __syncthreads();
    if (t < KS * 32) {
        int k = t >> 5, bb = t & 31;
        idx_out[k * B_TOTAL + b0 + bb] = idx_s[k][bb];
        val_out[k * B_TOTAL + b0 + bb] = val_s[k][bb];
    }
}

// ---------------------------------------------------------------------------
// K3a: expand sparse (idx,val) into dense 512 x 32768 coefficients.
// ---------------------------------------------------------------------------
__global__ void k_coeff(const int* __restrict__ idx, const float* __restrict__ val,
                        float* __restrict__ coeff) {
    const int bblk = blockIdx.x >> 3;
    const int jc   = blockIdx.x & 7;
    const int b    = bblk * 256 + threadIdx.x;
    int   I[KS]; float V[KS];
#pragma unroll
    for (int k = 0; k < KS; ++k) {
        I[k] = idx[k * B_TOTAL + b];
        V[k] = val[k * B_TOTAL + b];
    }
    const int j0 = jc * 64;
#pragma unroll 4
    for (int j = j0; j < j0 + 64; ++j) {
        float w = 0.f;
#pragma unroll
        for (int k = 0; k < KS; ++k) w = (I[k] == j) ? V[k] : w;
        coeff[j * B_TOTAL + b] = w;
    }
}

// ---------------------------------------------------------------------------
// K3b: z_out + loss. b-major compute (coalesced idx/val/dataT reads,
// D row L1-hot), LDS tile transpose for coalesced z_e-layout writes.
// ---------------------------------------------------------------------------
__global__ void k_recon(const float* __restrict__ dataT, const float* __restrict__ D,
                        const int* __restrict__ idx, const float* __restrict__ val,
                        float* __restrict__ zout, float* __restrict__ acc) {
    const int n   = blockIdx.x >> 4;
    const int hw0 = (blockIdx.x & 15) * 64;
    const int t   = threadIdx.x;
    __shared__ float lds[64][65];
    float sq = 0.f;
#pragma unroll
    for (int r = 0; r < 16; ++r) {
        int id = r * 256 + t;
        int c = id & 63, j = id >> 6;            // consecutive t -> consecutive c
        int f = n * 65536 + (hw0 + j) * 64 + c;  // = flat z_perm index
        int b = f & 32767;
        int m = f >> 15;                         // uniform per wave
        float zdl = 0.f;
#pragma unroll
        for (int k = 0; k < KS; ++k) {
            int   a = idx[k * B_TOTAL + b];
            float v = val[k * B_TOTAL + b];
            zdl = fmaf(v, D[m * NATOM + a], zdl);
        }
        float zp   = dataT[f];
        float diff = zdl - zp;
        lds[c][j] = zp + diff;
        sq = fmaf(diff, diff, sq);
    }
    __syncthreads();
#pragma unroll
    for (int r = 0; r < 16; ++r) {
        int id = r * 256 + t;
        int cc = id >> 6, i = id & 63;
        zout[n * 65536 + cc * 1024 + hw0 + i] = lds[cc][i];
    }
#pragma unroll
    for (int off = 32; off > 0; off >>= 1) sq += __shfl_xor(sq, off);
    __shared__ float red[4];
    if ((t & 63) == 0) red[t >> 6] = sq;
    __syncthreads();
    if (t == 0) atomicAdd(acc, red[0] + red[1] + red[2] + red[3]);
}

// ---------------------------------------------------------------------------
// K4: finalize loss = 1.25 * mean(diff^2)
// ---------------------------------------------------------------------------
__global__ void k_loss(const float* __restrict__ acc, float* __restrict__ out_loss) {
    if (threadIdx.x == 0 && blockIdx.x == 0)
        *out_loss = 1.25f * (*acc / 2097152.f);
}

// ---------------------------------------------------------------------------
extern "C" void kernel_launch(void* const* d_in, const int* in_sizes, int n_in,
                              void* d_out, int out_size, void* d_ws, size_t ws_size,
                              hipStream_t stream) {
    const float* ze = (const float*)d_in[0];
    const float* D  = (const float*)d_in[1];

    float* G     = (float*)d_ws;
    int*   idxp  = (int*)  ((char*)d_ws + (size_t)262144 * 4);
    float* valp  = (float*)((char*)d_ws + (size_t)(262144 + 163840) * 4);
    float* accp  = (float*)((char*)d_ws + (size_t)(262144 + 2 * 163840) * 4);
    float* dataT = (float*)((char*)d_ws + (size_t)(262144 + 2 * 163840 + 64) * 4);

    float* zout  = (float*)d_out;
    float* lossp = zout + 2097152;
    float* coeff = zout + 2097153;

    k_perm <<<512, 256, 0, stream>>>(ze, dataT);
    k_gram <<<512, 256, 0, stream>>>(D, G, accp);
    k_omp  <<<1024, 256, 0, stream>>>(dataT, D, G, idxp, valp);
    k_coeff<<<1024, 256, 0, stream>>>(idxp, valp, coeff);
    k_recon<<<512, 256, 0, stream>>>(dataT, D, idxp, valp, zout, accp);
    k_loss <<<1, 64, 0, stream>>>(accp, lossp);
}

// Round 5
// 185.849 us; speedup vs baseline: 1.7443x; 1.5888x over previous
//
#include <hip/hip_runtime.h>

#define B_TOTAL 32768
#define NATOM   512
#define MDIM    64
#define KS      5

// ---------------------------------------------------------------------------
// K0: materialize data^T: dataT[m][b] = z_perm_flat[m*32768+b]
// z_perm = transpose(z_e,(0,2,3,1)) reshaped row-major to (64, 32768).
// For z_e[n,c,h,w]:  m = 2n + (h>>4),  b = ((h&15)<<11)|(w<<6)|c.
// ---------------------------------------------------------------------------
__global__ void k_perm(const float* __restrict__ ze, float* __restrict__ dT) {
    const int n   = blockIdx.x >> 4;
    const int hw0 = (blockIdx.x & 15) * 64;
    const int t   = threadIdx.x;
    __shared__ float lds[64][65];
#pragma unroll
    for (int r = 0; r < 16; ++r) {
        int id = r * 256 + t;
        int c = id >> 6, i = id & 63;
        lds[c][i] = ze[n * 65536 + c * 1024 + hw0 + i];
    }
    __syncthreads();
#pragma unroll
    for (int r = 0; r < 16; ++r) {
        int id = r * 256 + t;
        int c = id & 63, j = id >> 6;
        int hw = hw0 + j;
        int h = hw >> 5, w = hw & 31;
        int m = (n << 1) | (h >> 4);
        int b = ((h & 15) << 11) | (w << 6) | c;
        dT[m * 32768 + b] = lds[c][j];
    }
}

// ---------------------------------------------------------------------------
// K1: G = D^T D, zero loss accumulator.
// ---------------------------------------------------------------------------
__global__ void k_gram(const float* __restrict__ D, float* __restrict__ G,
                       float* __restrict__ acc) {
    const int i = blockIdx.x;
    const int t = threadIdx.x;
    __shared__ float col[MDIM];
    if (t < MDIM) col[t] = D[t * NATOM + i];
    __syncthreads();
    for (int j = t; j < NATOM; j += 256) {
        float s = 0.f;
#pragma unroll
        for (int m = 0; m < MDIM; ++m) s = fmaf(col[m], D[m * NATOM + j], s);
        G[i * NATOM + j] = s;
    }
    if (i == 0 && t == 0) *acc = 0.f;
}

// ---------------------------------------------------------------------------
// K2: fused h_bar GEMM + per-column OMP.
// Phase 1: block = 4 waves, 32 b; wave computes h_bar for its 8 b.
// Re-stage via LDS so each 8-lane group owns ONE b, 64 atoms/lane
//   (lane p holds atoms n = 32q+4p+s, q=0..15).
// Phase 2: all 8 b of a wave run CONCURRENTLY (one per group).
// RACE FIX (R4 post-mortem): the re-stage reuses one LDS region twice; the
// WAR hazard (round-1 writes vs round-0 exec-masked reads) is NOT guaranteed
// by same-wave DS ordering once the code is spill-free and the LDS ops are
// back-to-back. Bracket each round with __syncthreads() (r is uniform).
// Private arrays (hb/key) use only compile-time indices / element-wise
// assigns so SROA keeps them in VGPRs (R3's float4 puns into hb = scratch).
// ---------------------------------------------------------------------------
__launch_bounds__(256, 2)
__global__ void k_omp(const float* __restrict__ data, const float* __restrict__ D,
                      const float* __restrict__ G, int* __restrict__ idx_out,
                      float* __restrict__ val_out) {
    const int t    = threadIdx.x;
    const int lane = t & 63;
    const int wv   = t >> 6;
    const int b0   = blockIdx.x * 32;

    __shared__ __align__(16) float data_s[32][68];
    __shared__ __align__(16) float stage[4][2048];   // 8KB per wave
    __shared__ int   idx_s[KS][32];
    __shared__ float val_s[KS][32];

    // stage data tile (64 m x 32 b), coalesced on b
#pragma unroll
    for (int r = 0; r < 8; ++r) {
        int id = r * 256 + t;
        int m = id >> 5, bb = id & 31;
        data_s[bb][m] = data[m * B_TOTAL + b0 + bb];
    }
    __syncthreads();

    const float4* __restrict__ D4 = (const float4*)D;
    const float4* __restrict__ G4 = (const float4*)G;

    // ---- phase 1: h_bar accumulators, 8 b x 8 atoms per lane ----
    float4 acc[8][2];
#pragma unroll
    for (int bb = 0; bb < 8; ++bb) {
        acc[bb][0] = make_float4(0.f, 0.f, 0.f, 0.f);
        acc[bb][1] = make_float4(0.f, 0.f, 0.f, 0.f);
    }
    const int bwbase = wv * 8;

#pragma unroll 4
    for (int c = 0; c < 16; ++c) {
        float4 df[4][2];
#pragma unroll
        for (int mm = 0; mm < 4; ++mm) {
            df[mm][0] = D4[(c * 4 + mm) * 128 + lane];
            df[mm][1] = D4[(c * 4 + mm) * 128 + 64 + lane];
        }
#pragma unroll
        for (int bb = 0; bb < 8; ++bb) {
            const float4 dv = *(const float4*)&data_s[bwbase + bb][c * 4];
            const float dm[4] = {dv.x, dv.y, dv.z, dv.w};
#pragma unroll
            for (int mm = 0; mm < 4; ++mm) {
                acc[bb][0].x = fmaf(df[mm][0].x, dm[mm], acc[bb][0].x);
                acc[bb][0].y = fmaf(df[mm][0].y, dm[mm], acc[bb][0].y);
                acc[bb][0].z = fmaf(df[mm][0].z, dm[mm], acc[bb][0].z);
                acc[bb][0].w = fmaf(df[mm][0].w, dm[mm], acc[bb][0].w);
                acc[bb][1].x = fmaf(df[mm][1].x, dm[mm], acc[bb][1].x);
                acc[bb][1].y = fmaf(df[mm][1].y, dm[mm], acc[bb][1].y);
                acc[bb][1].z = fmaf(df[mm][1].z, dm[mm], acc[bb][1].z);
                acc[bb][1].w = fmaf(df[mm][1].w, dm[mm], acc[bb][1].w);
            }
        }
    }

    // ---- re-stage: acc(8b x 8 atoms) -> hb(64 atoms of group's b) ----
    // stage[wv][q2*512 + n] = h_bar[n] for b = b0 + bwbase + (r*4+q2).
    const int g = lane >> 3;       // group = b within wave's 8
    const int p = lane & 7;        // lane within group
    float hb[64];
#pragma unroll
    for (int r = 0; r < 2; ++r) {
        __syncthreads();           // round r-1 reads complete before overwrite
#pragma unroll
        for (int q2 = 0; q2 < 4; ++q2) {
            int bb = r * 4 + q2;
            *(float4*)&stage[wv][q2 * 512 + 4 * lane]       = acc[bb][0];
            *(float4*)&stage[wv][q2 * 512 + 256 + 4 * lane] = acc[bb][1];
        }
        __syncthreads();           // writes committed before reads
        if ((g >> 2) == r) {
#pragma unroll
            for (int q = 0; q < 16; ++q) {
                const float4 v =
                    *(const float4*)&stage[wv][(g & 3) * 512 + 32 * q + 4 * p];
                hb[4 * q + 0] = v.x;
                hb[4 * q + 1] = v.y;
                hb[4 * q + 2] = v.z;
                hb[4 * q + 3] = v.w;
            }
        }
    }

    // ---- phase 2: OMP, 8 concurrent b (one per 8-lane group) ----
    float key[64];
#pragma unroll
    for (int e = 0; e < 64; ++e) key[e] = fabsf(hb[e]);

    unsigned msk0 = 0u, msk1 = 0u;
    int   I[KS];
    float xs[KS];
    float gsel[KS];
    float Lm[15];                   // packed lower-tri

#pragma unroll
    for (int k = 0; k < KS; ++k) {
        // --- local argmax over 64 register keys (mask pre-folded as -1) ---
        float bv = key[0]; int be = 0; float bhb = hb[0];
#pragma unroll
        for (int e = 1; e < 64; ++e) {
            bool gt = key[e] > bv;          // strict > keeps lowest e (n asc.)
            bv  = gt ? key[e] : bv;
            be  = gt ? e      : be;
            bhb = gt ? hb[e]  : bhb;
        }
        int bn = 32 * (be >> 2) + 4 * p + (be & 3);
        // --- 3-step reduce across the 8-lane group ---
#pragma unroll
        for (int off = 1; off < 8; off <<= 1) {
            float ov  = __shfl_xor(bv, off);
            int   on  = __shfl_xor(bn, off);
            float ohb = __shfl_xor(bhb, off);
            bool take = (ov > bv) || (ov == bv && on < bn);
            bv = take ? ov : bv; bn = take ? on : bn; bhb = take ? ohb : bhb;
        }
        const int nsel = bn;                // group-uniform
        I[k]    = nsel;
        gsel[k] = bhb;                      // = h_bar[nsel] (original), exact

        // mask the selected atom for future scans
        {
            int own  = (nsel >> 2) & 7;
            int esel = ((nsel >> 5) << 2) | (nsel & 3);
            if (p == own) {
                if (esel < 32) msk0 |= 1u << esel;
                else           msk1 |= 1u << (esel - 32);
            }
        }

        // --- Cholesky update of L ---
        if (k > 0) {
            float gk[KS - 1], w[KS - 1];
#pragma unroll
            for (int ti = 0; ti < KS - 1; ++ti)
                if (ti < k) gk[ti] = G[I[ti] * NATOM + nsel];
#pragma unroll
            for (int r = 0; r < KS - 1; ++r) {
                if (r < k) {
                    float s = gk[r];
#pragma unroll
                    for (int cc = 0; cc < KS - 1; ++cc)
                        if (cc < r) s -= Lm[r * (r + 1) / 2 + cc] * w[cc];
                    w[r] = s / Lm[r * (r + 1) / 2 + r];
                }
            }
            float s2 = 0.f;
#pragma unroll
            for (int r = 0; r < KS - 1; ++r) if (r < k) s2 += w[r] * w[r];
            float wc = sqrtf(fmaxf(0.f, 1.f - s2));
#pragma unroll
            for (int cc = 0; cc < KS - 1; ++cc)
                if (cc < k) Lm[k * (k + 1) / 2 + cc] = w[cc];
            Lm[k * (k + 1) / 2 + k] = wc;
        } else {
            Lm[0] = 1.f;
        }

        // --- solve L y = gsel ; L^T x = y (replicated within group) ---
        float y[KS];
#pragma unroll
        for (int r = 0; r <= k; ++r) {
            float s = gsel[r];
#pragma unroll
            for (int cc = 0; cc < r; ++cc) s -= Lm[r * (r + 1) / 2 + cc] * y[cc];
            y[r] = s / Lm[r * (r + 1) / 2 + r];
        }
#pragma unroll
        for (int r = k; r >= 0; --r) {
            float s = y[r];
#pragma unroll
            for (int cc = r + 1; cc <= k; ++cc) s -= Lm[cc * (cc + 1) / 2 + r] * xs[cc];
            xs[r] = s / Lm[r * (r + 1) / 2 + r];
        }

        // --- fused beta + key update (no beta[] array; ascending-ti fma) ---
        if (k < KS - 1) {
#pragma unroll
            for (int q = 0; q < 16; ++q) {
                float bx = 0.f, by = 0.f, bz = 0.f, bw = 0.f;
#pragma unroll
                for (int ti = 0; ti < KS - 1; ++ti) {
                    if (ti <= k) {
                        const float4 gc = G4[I[ti] * 128 + 8 * q + p];
                        bx = fmaf(xs[ti], gc.x, bx);
                        by = fmaf(xs[ti], gc.y, by);
                        bz = fmaf(xs[ti], gc.z, bz);
                        bw = fmaf(xs[ti], gc.w, bw);
                    }
                }
                {
                    float d0 = hb[4 * q + 0] - bx;
                    float d1 = hb[4 * q + 1] - by;
                    float d2 = hb[4 * q + 2] - bz;
                    float d3 = hb[4 * q + 3] - bw;
                    const int e0 = 4 * q;
                    bool m0 = (e0 + 0 < 32) ? ((msk0 >> (e0 + 0)) & 1u) : ((msk1 >> (e0 - 32)) & 1u);
                    bool m1 = (e0 + 1 < 32) ? ((msk0 >> (e0 + 1)) & 1u) : ((msk1 >> (e0 + 1 - 32)) & 1u);
                    bool m2 = (e0 + 2 < 32) ? ((msk0 >> (e0 + 2)) & 1u) : ((msk1 >> (e0 + 2 - 32)) & 1u);
                    bool m3 = (e0 + 3 < 32) ? ((msk0 >> (e0 + 3)) & 1u) : ((msk1 >> (e0 + 3 - 32)) & 1u);
                    key[e0 + 0] = m0 ? -1.f : fabsf(d0);
                    key[e0 + 1] = m1 ? -1.f : fabsf(d1);
                    key[e0 + 2] = m2 ? -1.f : fabsf(d2);
                    key[e0 + 3] = m3 ? -1.f : fabsf(d3);
                }
            }
        }
    }

    if (p == 0) {
#pragma unroll
        for (int k = 0; k < KS; ++k) {
            idx_s[k][wv * 8 + g] = I[k];
            val_s[k][wv * 8 + g] = xs[k];
        }
    }
    __syncthreads();
    if (t < KS * 32) {
        int k = t >> 5, bb = t & 31;
        idx_out[k * B_TOTAL + b0 + bb] = idx_s[k][bb];
        val_out[k * B_TOTAL + b0 + bb] = val_s[k][bb];
    }
}

// ---------------------------------------------------------------------------
// K3a: expand sparse (idx,val) into dense 512 x 32768 coefficients.
// ---------------------------------------------------------------------------
__global__ void k_coeff(const int* __restrict__ idx, const float* __restrict__ val,
                        float* __restrict__ coeff) {
    const int bblk = blockIdx.x >> 3;
    const int jc   = blockIdx.x & 7;
    const int b    = bblk * 256 + threadIdx.x;
    int   I[KS]; float V[KS];
#pragma unroll
    for (int k = 0; k < KS; ++k) {
        I[k] = idx[k * B_TOTAL + b];
        V[k] = val[k * B_TOTAL + b];
    }
    const int j0 = jc * 64;
#pragma unroll 4
    for (int j = j0; j < j0 + 64; ++j) {
        float w = 0.f;
#pragma unroll
        for (int k = 0; k < KS; ++k) w = (I[k] == j) ? V[k] : w;
        coeff[j * B_TOTAL + b] = w;
    }
}

// ---------------------------------------------------------------------------
// K3b: z_out + loss. b-major compute (coalesced idx/val/dataT reads,
// D row L1-hot), LDS tile transpose for coalesced z_e-layout writes.
// ---------------------------------------------------------------------------
__global__ void k_recon(const float* __restrict__ dataT, const float* __restrict__ D,
                        const int* __restrict__ idx, const float* __restrict__ val,
                        float* __restrict__ zout, float* __restrict__ acc) {
    const int n   = blockIdx.x >> 4;
    const int hw0 = (blockIdx.x & 15) * 64;
    const int t   = threadIdx.x;
    __shared__ float lds[64][65];
    float sq = 0.f;
#pragma unroll
    for (int r = 0; r < 16; ++r) {
        int id = r * 256 + t;
        int c = id & 63, j = id >> 6;
        int f = n * 65536 + (hw0 + j) * 64 + c;
        int b = f & 32767;
        int m = f >> 15;
        float zdl = 0.f;
#pragma unroll
        for (int k = 0; k < KS; ++k) {
            int   a = idx[k * B_TOTAL + b];
            float v = val[k * B_TOTAL + b];
            zdl = fmaf(v, D[m * NATOM + a], zdl);
        }
        float zp   = dataT[f];
        float diff = zdl - zp;
        lds[c][j] = zp + diff;
        sq = fmaf(diff, diff, sq);
    }
    __syncthreads();
#pragma unroll
    for (int r = 0; r < 16; ++r) {
        int id = r * 256 + t;
        int cc = id >> 6, i = id & 63;
        zout[n * 65536 + cc * 1024 + hw0 + i] = lds[cc][i];
    }
#pragma unroll
    for (int off = 32; off > 0; off >>= 1) sq += __shfl_xor(sq, off);
    __shared__ float red[4];
    if ((t & 63) == 0) red[t >> 6] = sq;
    __syncthreads();
    if (t == 0) atomicAdd(acc, red[0] + red[1] + red[2] + red[3]);
}

// ---------------------------------------------------------------------------
// K4: finalize loss = 1.25 * mean(diff^2)
// ---------------------------------------------------------------------------
__global__ void k_loss(const float* __restrict__ acc, float* __restrict__ out_loss) {
    if (threadIdx.x == 0 && blockIdx.x == 0)
        *out_loss = 1.25f * (*acc / 2097152.f);
}

// ---------------------------------------------------------------------------
extern "C" void kernel_launch(void* const* d_in, const int* in_sizes, int n_in,
                              void* d_out, int out_size, void* d_ws, size_t ws_size,
                              hipStream_t stream) {
    const float* ze = (const float*)d_in[0];
    const float* D  = (const float*)d_in[1];

    float* G     = (float*)d_ws;
    int*   idxp  = (int*)  ((char*)d_ws + (size_t)262144 * 4);
    float* valp  = (float*)((char*)d_ws + (size_t)(262144 + 163840) * 4);
    float* accp  = (float*)((char*)d_ws + (size_t)(262144 + 2 * 163840) * 4);
    float* dataT = (float*)((char*)d_ws + (size_t)(262144 + 2 * 163840 + 64) * 4);

    float* zout  = (float*)d_out;
    float* lossp = zout + 2097152;
    float* coeff = zout + 2097153;

    k_perm <<<512, 256, 0, stream>>>(ze, dataT);
    k_gram <<<512, 256, 0, stream>>>(D, G, accp);
    k_omp  <<<1024, 256, 0, stream>>>(dataT, D, G, idxp, valp);
    k_coeff<<<1024, 256, 0, stream>>>(idxp, valp, coeff);
    k_recon<<<512, 256, 0, stream>>>(dataT, D, idxp, valp, zout, accp);
    k_loss <<<1, 64, 0, stream>>>(accp, lossp);
}